// Round 15
// baseline (1881.260 us; speedup 1.0000x reference)
//
#include <hip/hip_runtime.h>
#include <math.h>

#define B_ 1024
#define D_ 2048
#define H_ 2048
#define E_ 16
#define K_ 8
#define KEEP_ 6
#define EXP_ID_ 0

// ---------------- ws layout ----------------
#define WS_OUTALL 0
#define WS_IDX    134217728
#define WS_VALS   (134217728 + 32768)
#define WS_ENERGY (134217728 + 65536)
#define WS_CNT    (134217728 + 98304)
#define WS_ROWS   (134217728 + 98560)

// ---------------- 0. init: zero per-expert row counters ----------------
__global__ void init_cnt_kernel(int* __restrict__ cnt) {
  if (threadIdx.x < E_) cnt[threadIdx.x] = 0;
}

// ---------------- 1. gating: one wave per row, f64; emit row lists ----------
__global__ __launch_bounds__(64) void gate_kernel(
    const float* __restrict__ x, const float* __restrict__ Wg,
    const float* __restrict__ bg, int* __restrict__ idx, float* __restrict__ vals,
    int* __restrict__ cnt, int* __restrict__ rows) {
  const int b = blockIdx.x;
  const int lane = threadIdx.x;
  double acc[E_];
#pragma unroll
  for (int e = 0; e < E_; ++e) acc[e] = 0.0;
  for (int d = lane; d < D_; d += 64) {
    double xv = (double)x[(size_t)b * D_ + d];
    const float* w = Wg + (size_t)d * E_;
#pragma unroll
    for (int e = 0; e < E_; ++e) acc[e] = fma(xv, (double)w[e], acc[e]);
  }
  for (int off = 32; off > 0; off >>= 1) {
#pragma unroll
    for (int e = 0; e < E_; ++e) acc[e] += __shfl_down(acc[e], off, 64);
  }
  if (lane == 0) {
    double logit[E_];
#pragma unroll
    for (int e = 0; e < E_; ++e) logit[e] = acc[e] + (double)bg[e];
    double m = logit[0];
#pragma unroll
    for (int e = 1; e < E_; ++e) m = fmax(m, logit[e]);
    double p[E_], s = 0.0;
#pragma unroll
    for (int e = 0; e < E_; ++e) { p[e] = exp(logit[e] - m); s += p[e]; }
#pragma unroll
    for (int e = 0; e < E_; ++e) p[e] = p[e] / s;
    unsigned taken = 0;
    for (int j = 0; j < K_; ++j) {
      int best = -1; double bv = -1.0;
#pragma unroll
      for (int e = 0; e < E_; ++e)
        if (!((taken >> e) & 1u) && p[e] > bv) { bv = p[e]; best = e; }
      taken |= (1u << best);
      idx[b * K_ + j] = best;
      vals[b * K_ + j] = (float)bv;
    }
    taken |= 1u;   // rep expert always needed
#pragma unroll
    for (int e = 0; e < E_; ++e) {
      if ((taken >> e) & 1u) {
        int p2 = atomicAdd(&cnt[e], 1);
        rows[e * B_ + p2] = b;
      }
    }
  }
}

// ---- 2. GEMM (f64 accumulate = truth), row-gathered, 4x8/thread, BN=128 ----
// Per-output sequential k-order identical to verified R13 -> bits identical.
#define BM 64
#define BN 128
#define BK 16

__global__ __launch_bounds__(256) void gemm_expert_kernel(
    const float* __restrict__ X, const float* __restrict__ We,
    const float* __restrict__ be, float* __restrict__ out_all,
    const int* __restrict__ cnt, const int* __restrict__ rows) {
  const int e  = blockIdx.z;
  const int nrows = cnt[e];
  const int m0 = blockIdx.y * BM;
  if (m0 >= nrows) return;
  const int n0 = blockIdx.x * BN;
  const float* Bmat = We + (size_t)e * D_ * H_;
  const int* rl = rows + e * B_;

  __shared__ double As[BM][BK + 2];   // [64][18]  9216 B, rows 144B (16B-aligned)
  __shared__ double Bs[BK][BN + 2];   // [16][130] 16640 B, rows 1040B

  const int tid = threadIdx.x;
  const int tx = tid % 16, ty = tid / 16;   // ty in [0,16): 4 output rows each
  const int arow  = tid >> 2;               // [0,64)
  const int acol4 = (tid & 3) * 4;          // {0,4,8,12}
  const int brow  = tid >> 4;               // [0,16)
  const int bcol8 = (tid & 15) * 8;         // {0..120}

  const int gidx = m0 + arow;
  const int grow = rl[(gidx < nrows) ? gidx : (nrows - 1)];

  // lane's 8 output cols: {c0,c0+1, c1,c1+1, c2,c2+1, c3,c3+1}
  const int c0 = tx * 2;
  const int c1 = tx * 2 + 32;
  const int c2 = tx * 2 + 64;
  const int c3 = tx * 2 + 96;

  double acc[4][8] = {};

  for (int k0 = 0; k0 < D_; k0 += BK) {
    float4 av  = *(const float4*)(X + (size_t)grow * D_ + k0 + acol4);
    float4 bv0 = *(const float4*)(Bmat + (size_t)(k0 + brow) * H_ + n0 + bcol8);
    float4 bv1 = *(const float4*)(Bmat + (size_t)(k0 + brow) * H_ + n0 + bcol8 + 4);
    __syncthreads();
    *(double2*)&As[arow][acol4 + 0] = make_double2((double)av.x, (double)av.y);
    *(double2*)&As[arow][acol4 + 2] = make_double2((double)av.z, (double)av.w);
    *(double2*)&Bs[brow][bcol8 + 0] = make_double2((double)bv0.x, (double)bv0.y);
    *(double2*)&Bs[brow][bcol8 + 2] = make_double2((double)bv0.z, (double)bv0.w);
    *(double2*)&Bs[brow][bcol8 + 4] = make_double2((double)bv1.x, (double)bv1.y);
    *(double2*)&Bs[brow][bcol8 + 6] = make_double2((double)bv1.z, (double)bv1.w);
    __syncthreads();
#pragma unroll
    for (int kk = 0; kk < BK; ++kk) {
      double a0 = As[ty * 4 + 0][kk];
      double a1 = As[ty * 4 + 1][kk];
      double a2 = As[ty * 4 + 2][kk];
      double a3 = As[ty * 4 + 3][kk];
      double2 b0 = *(const double2*)&Bs[kk][c0];
      double2 b1 = *(const double2*)&Bs[kk][c1];
      double2 b2 = *(const double2*)&Bs[kk][c2];
      double2 b3 = *(const double2*)&Bs[kk][c3];
      acc[0][0] = fma(a0, b0.x, acc[0][0]);
      acc[0][1] = fma(a0, b0.y, acc[0][1]);
      acc[0][2] = fma(a0, b1.x, acc[0][2]);
      acc[0][3] = fma(a0, b1.y, acc[0][3]);
      acc[0][4] = fma(a0, b2.x, acc[0][4]);
      acc[0][5] = fma(a0, b2.y, acc[0][5]);
      acc[0][6] = fma(a0, b3.x, acc[0][6]);
      acc[0][7] = fma(a0, b3.y, acc[0][7]);
      acc[1][0] = fma(a1, b0.x, acc[1][0]);
      acc[1][1] = fma(a1, b0.y, acc[1][1]);
      acc[1][2] = fma(a1, b1.x, acc[1][2]);
      acc[1][3] = fma(a1, b1.y, acc[1][3]);
      acc[1][4] = fma(a1, b2.x, acc[1][4]);
      acc[1][5] = fma(a1, b2.y, acc[1][5]);
      acc[1][6] = fma(a1, b3.x, acc[1][6]);
      acc[1][7] = fma(a1, b3.y, acc[1][7]);
      acc[2][0] = fma(a2, b0.x, acc[2][0]);
      acc[2][1] = fma(a2, b0.y, acc[2][1]);
      acc[2][2] = fma(a2, b1.x, acc[2][2]);
      acc[2][3] = fma(a2, b1.y, acc[2][3]);
      acc[2][4] = fma(a2, b2.x, acc[2][4]);
      acc[2][5] = fma(a2, b2.y, acc[2][5]);
      acc[2][6] = fma(a2, b3.x, acc[2][6]);
      acc[2][7] = fma(a2, b3.y, acc[2][7]);
      acc[3][0] = fma(a3, b0.x, acc[3][0]);
      acc[3][1] = fma(a3, b0.y, acc[3][1]);
      acc[3][2] = fma(a3, b1.x, acc[3][2]);
      acc[3][3] = fma(a3, b1.y, acc[3][3]);
      acc[3][4] = fma(a3, b2.x, acc[3][4]);
      acc[3][5] = fma(a3, b2.y, acc[3][5]);
      acc[3][6] = fma(a3, b3.x, acc[3][6]);
      acc[3][7] = fma(a3, b3.y, acc[3][7]);
    }
  }
#pragma unroll
  for (int i = 0; i < 4; ++i) {
    const int ridx = m0 + ty * 4 + i;
    if (ridx < nrows) {
      const int m = rl[ridx];
      float* dst = out_all + ((size_t)m * E_ + e) * H_ + n0;
      const double* bb = (const double*)0;
      (void)bb;
      float2 p0, p1, p2, p3;
      p0.x = (float)(acc[i][0] + (double)be[(size_t)e * H_ + n0 + c0 + 0]);
      p0.y = (float)(acc[i][1] + (double)be[(size_t)e * H_ + n0 + c0 + 1]);
      p1.x = (float)(acc[i][2] + (double)be[(size_t)e * H_ + n0 + c1 + 0]);
      p1.y = (float)(acc[i][3] + (double)be[(size_t)e * H_ + n0 + c1 + 1]);
      p2.x = (float)(acc[i][4] + (double)be[(size_t)e * H_ + n0 + c2 + 0]);
      p2.y = (float)(acc[i][5] + (double)be[(size_t)e * H_ + n0 + c2 + 1]);
      p3.x = (float)(acc[i][6] + (double)be[(size_t)e * H_ + n0 + c3 + 0]);
      p3.y = (float)(acc[i][7] + (double)be[(size_t)e * H_ + n0 + c3 + 1]);
      *(float2*)(dst + c0) = p0;
      *(float2*)(dst + c1) = p1;
      *(float2*)(dst + c2) = p2;
      *(float2*)(dst + c3) = p3;
    }
  }
}

// ---- 3. energy: bit-replica of numpy f32 logsumexp (verified R11) ----
__global__ __launch_bounds__(256) void energy_kernel(
    const float* __restrict__ out_all, const int* __restrict__ idx,
    float* __restrict__ energy) {
  const int b = blockIdx.x, j = blockIdx.y, t = threadIdx.x;
  const int e = idx[b * K_ + j];
  if (e == EXP_ID_) {
    if (t == 0) energy[b * K_ + j] = 1.0f + (float)log(2048.0);
    return;
  }
  const float* rep = out_all + ((size_t)b * E_ + EXP_ID_) * H_;
  const float* ok  = out_all + ((size_t)b * E_ + e) * H_;

  __shared__ float cs[H_];
  __shared__ float red[256];
  __shared__ float chain[128];

  float mx = -2.0f;
  for (int h = t; h < H_; h += 256) {
    float r = rep[h], o = ok[h];
    float num = r * o;
    float den = fabsf(r) * fabsf(o) + 1e-8f;
    float c = num / den;
    cs[h] = c;
    mx = fmaxf(mx, c);
  }
  red[t] = mx;
  __syncthreads();
  for (int off = 128; off > 0; off >>= 1) {
    if (t < off) red[t] = fmaxf(red[t], red[t + off]);
    __syncthreads();
  }
  const float m = red[0];
  __syncthreads();

  if (t < 128) {
    const int blk = t >> 3, jj = t & 7;
    const float* base = cs + blk * 128;
    float d0 = base[jj] - m;
    float r = (float)exp((double)d0);
#pragma unroll
    for (int q = 1; q < 16; ++q) {
      float dq = base[q * 8 + jj] - m;
      float term = (float)exp((double)dq);
      r = r + term;
    }
    chain[t] = r;
  }
  __syncthreads();

  if (t == 0) {
    float Bsum[16];
#pragma unroll
    for (int blk = 0; blk < 16; ++blk) {
      const float* c8 = chain + blk * 8;
      float s01 = c8[0] + c8[1];
      float s23 = c8[2] + c8[3];
      float s45 = c8[4] + c8[5];
      float s67 = c8[6] + c8[7];
      Bsum[blk] = (s01 + s23) + (s45 + s67);
    }
    float C[8], D[4], Ee[2];
#pragma unroll
    for (int i = 0; i < 8; ++i) C[i] = Bsum[2 * i] + Bsum[2 * i + 1];
#pragma unroll
    for (int i = 0; i < 4; ++i) D[i] = C[2 * i] + C[2 * i + 1];
#pragma unroll
    for (int i = 0; i < 2; ++i) Ee[i] = D[2 * i] + D[2 * i + 1];
    float S = Ee[0] + Ee[1];
    energy[b * K_ + j] = m + (float)log((double)S);
  }
}

// ---- 4. select: stable rank on f32 E bits (exact ties -> lower j), keep 6 ----
__global__ __launch_bounds__(256) void final_kernel(
    const float* __restrict__ out_all, const int* __restrict__ idx,
    const float* __restrict__ vals, const float* __restrict__ energy,
    float* __restrict__ out) {
  const int b = blockIdx.x;
  const int h = blockIdx.y * 256 + threadIdx.x;
  float En[K_];
#pragma unroll
  for (int j = 0; j < K_; ++j) En[j] = energy[b * K_ + j];
  double s = 0.0;
#pragma unroll
  for (int j = 0; j < K_; ++j) {
    int pos = 0;
#pragma unroll
    for (int j2 = 0; j2 < K_; ++j2)
      pos += (En[j2] < En[j]) || (En[j2] == En[j] && j2 < j);
    if (pos < KEEP_) {
      int e = idx[b * K_ + j];
      s += (double)vals[b * K_ + j] *
           (double)out_all[((size_t)b * E_ + e) * H_ + h];
    }
  }
  out[(size_t)b * H_ + h] = (float)s;
}

// ---------------- launch ----------------
extern "C" void kernel_launch(void* const* d_in, const int* in_sizes, int n_in,
                              void* d_out, int out_size, void* d_ws, size_t ws_size,
                              hipStream_t stream) {
  const float* x  = (const float*)d_in[0];
  const float* Wg = (const float*)d_in[1];
  const float* bg = (const float*)d_in[2];
  const float* We = (const float*)d_in[3];
  const float* be = (const float*)d_in[4];
  float* out = (float*)d_out;

  char* ws = (char*)d_ws;
  float* out_all = (float*)(ws + WS_OUTALL);
  int*   idx     = (int*)(ws + WS_IDX);
  float* vals    = (float*)(ws + WS_VALS);
  float* energy  = (float*)(ws + WS_ENERGY);
  int*   cnt     = (int*)(ws + WS_CNT);
  int*   rows    = (int*)(ws + WS_ROWS);

  init_cnt_kernel<<<dim3(1), dim3(64), 0, stream>>>(cnt);

  gate_kernel<<<dim3(B_), dim3(64), 0, stream>>>(x, Wg, bg, idx, vals, cnt, rows);

  gemm_expert_kernel<<<dim3(H_ / BN, B_ / BM, E_), dim3(256), 0, stream>>>(
      x, We, be, out_all, cnt, rows);

  energy_kernel<<<dim3(B_, K_), dim3(256), 0, stream>>>(out_all, idx, energy);

  final_kernel<<<dim3(B_, H_ / 256), dim3(256), 0, stream>>>(
      out_all, idx, vals, energy, out);
}

// Round 16
// 1819.098 us; speedup vs baseline: 1.0342x; 1.0342x over previous
//
#include <hip/hip_runtime.h>
#include <math.h>

#define B_ 1024
#define D_ 2048
#define H_ 2048
#define E_ 16
#define K_ 8
#define KEEP_ 6
#define EXP_ID_ 0

// ---------------- ws layout ----------------
#define WS_OUTALL 0
#define WS_IDX    134217728
#define WS_VALS   (134217728 + 32768)
#define WS_ENERGY (134217728 + 65536)
#define WS_CNT    (134217728 + 98304)
#define WS_ROWS   (134217728 + 98560)

// ---------------- 0. init: zero per-expert row counters ----------------
__global__ void init_cnt_kernel(int* __restrict__ cnt) {
  if (threadIdx.x < E_) cnt[threadIdx.x] = 0;
}

// ---------------- 1. gating: one wave per row, f64; emit row lists ----------
__global__ __launch_bounds__(64) void gate_kernel(
    const float* __restrict__ x, const float* __restrict__ Wg,
    const float* __restrict__ bg, int* __restrict__ idx, float* __restrict__ vals,
    int* __restrict__ cnt, int* __restrict__ rows) {
  const int b = blockIdx.x;
  const int lane = threadIdx.x;
  double acc[E_];
#pragma unroll
  for (int e = 0; e < E_; ++e) acc[e] = 0.0;
  for (int d = lane; d < D_; d += 64) {
    double xv = (double)x[(size_t)b * D_ + d];
    const float* w = Wg + (size_t)d * E_;
#pragma unroll
    for (int e = 0; e < E_; ++e) acc[e] = fma(xv, (double)w[e], acc[e]);
  }
  for (int off = 32; off > 0; off >>= 1) {
#pragma unroll
    for (int e = 0; e < E_; ++e) acc[e] += __shfl_down(acc[e], off, 64);
  }
  if (lane == 0) {
    double logit[E_];
#pragma unroll
    for (int e = 0; e < E_; ++e) logit[e] = acc[e] + (double)bg[e];
    double m = logit[0];
#pragma unroll
    for (int e = 1; e < E_; ++e) m = fmax(m, logit[e]);
    double p[E_], s = 0.0;
#pragma unroll
    for (int e = 0; e < E_; ++e) { p[e] = exp(logit[e] - m); s += p[e]; }
#pragma unroll
    for (int e = 0; e < E_; ++e) p[e] = p[e] / s;
    unsigned taken = 0;
    for (int j = 0; j < K_; ++j) {
      int best = -1; double bv = -1.0;
#pragma unroll
      for (int e = 0; e < E_; ++e)
        if (!((taken >> e) & 1u) && p[e] > bv) { bv = p[e]; best = e; }
      taken |= (1u << best);
      idx[b * K_ + j] = best;
      vals[b * K_ + j] = (float)bv;
    }
    taken |= 1u;   // rep expert always needed
#pragma unroll
    for (int e = 0; e < E_; ++e) {
      if ((taken >> e) & 1u) {
        int p2 = atomicAdd(&cnt[e], 1);
        rows[e * B_ + p2] = b;
      }
    }
  }
}

// ---- 2. GEMM (f64, R13-proven 4x4 tile) + double-buffered LDS pipeline ----
// Per-output sequential k-order identical to verified R13 -> bits identical.
#define BM 64
#define BN 64
#define BK 16

__global__ __launch_bounds__(256) void gemm_expert_kernel(
    const float* __restrict__ X, const float* __restrict__ We,
    const float* __restrict__ be, float* __restrict__ out_all,
    const int* __restrict__ cnt, const int* __restrict__ rows) {
  const int e  = blockIdx.z;
  const int nrows = cnt[e];
  const int m0 = blockIdx.y * BM;
  if (m0 >= nrows) return;
  const int n0 = blockIdx.x * BN;
  const float* Bmat = We + (size_t)e * D_ * H_;
  const int* rl = rows + e * B_;

  __shared__ double As[2][BM][BK + 2];   // 2 x 9216 B
  __shared__ double Bs[2][BK][BN + 2];   // 2 x 8448 B   total 35328 B

  const int tid = threadIdx.x;
  const int tx = tid % 16, ty = tid / 16;
  const int arow  = tid >> 2;               // [0,64)
  const int acol4 = (tid & 3) * 4;          // {0,4,8,12}
  const int brow  = tid >> 4;               // [0,16)
  const int bcol4 = (tid & 15) * 4;         // {0..60}

  const int gidx = m0 + arow;
  const int grow = rl[(gidx < nrows) ? gidx : (nrows - 1)];
  const float* aptr = X + (size_t)grow * D_;
  const float* bptr = Bmat + (size_t)brow * H_ + n0 + bcol4;

  const int c0 = tx * 2;
  const int c1 = tx * 2 + 32;

  double acc[4][4] = {};

  // prologue: stage tile 0 into buf 0
  {
    float4 av = *(const float4*)(aptr + acol4);
    float4 bv = *(const float4*)(bptr);
    *(double2*)&As[0][arow][acol4 + 0] = make_double2((double)av.x, (double)av.y);
    *(double2*)&As[0][arow][acol4 + 2] = make_double2((double)av.z, (double)av.w);
    *(double2*)&Bs[0][brow][bcol4 + 0] = make_double2((double)bv.x, (double)bv.y);
    *(double2*)&Bs[0][brow][bcol4 + 2] = make_double2((double)bv.z, (double)bv.w);
  }
  __syncthreads();

  int cur = 0;
  for (int k0 = 0; k0 < D_; k0 += BK) {
    // issue next-tile loads BEFORE compute: latency hides under the FMAs
    float4 av_n, bv_n;
    const bool more = (k0 + BK) < D_;
    if (more) {
      av_n = *(const float4*)(aptr + (k0 + BK) + acol4);
      bv_n = *(const float4*)(bptr + (size_t)(k0 + BK) * H_);
    }
#pragma unroll
    for (int kk = 0; kk < BK; ++kk) {
      double a0 = As[cur][ty * 4 + 0][kk];
      double a1 = As[cur][ty * 4 + 1][kk];
      double a2 = As[cur][ty * 4 + 2][kk];
      double a3 = As[cur][ty * 4 + 3][kk];
      double2 b01 = *(const double2*)&Bs[cur][kk][c0];
      double2 b23 = *(const double2*)&Bs[cur][kk][c1];
      acc[0][0] = fma(a0, b01.x, acc[0][0]);
      acc[0][1] = fma(a0, b01.y, acc[0][1]);
      acc[0][2] = fma(a0, b23.x, acc[0][2]);
      acc[0][3] = fma(a0, b23.y, acc[0][3]);
      acc[1][0] = fma(a1, b01.x, acc[1][0]);
      acc[1][1] = fma(a1, b01.y, acc[1][1]);
      acc[1][2] = fma(a1, b23.x, acc[1][2]);
      acc[1][3] = fma(a1, b23.y, acc[1][3]);
      acc[2][0] = fma(a2, b01.x, acc[2][0]);
      acc[2][1] = fma(a2, b01.y, acc[2][1]);
      acc[2][2] = fma(a2, b23.x, acc[2][2]);
      acc[2][3] = fma(a2, b23.y, acc[2][3]);
      acc[3][0] = fma(a3, b01.x, acc[3][0]);
      acc[3][1] = fma(a3, b01.y, acc[3][1]);
      acc[3][2] = fma(a3, b23.x, acc[3][2]);
      acc[3][3] = fma(a3, b23.y, acc[3][3]);
    }
    if (more) {
      const int nxt = cur ^ 1;
      *(double2*)&As[nxt][arow][acol4 + 0] = make_double2((double)av_n.x, (double)av_n.y);
      *(double2*)&As[nxt][arow][acol4 + 2] = make_double2((double)av_n.z, (double)av_n.w);
      *(double2*)&Bs[nxt][brow][bcol4 + 0] = make_double2((double)bv_n.x, (double)bv_n.y);
      *(double2*)&Bs[nxt][brow][bcol4 + 2] = make_double2((double)bv_n.z, (double)bv_n.w);
      __syncthreads();     // one barrier per iteration
      cur = nxt;
    }
  }
#pragma unroll
  for (int i = 0; i < 4; ++i) {
    const int ridx = m0 + ty * 4 + i;
    if (ridx < nrows) {
      const int m = rl[ridx];
      float* dst = out_all + ((size_t)m * E_ + e) * H_ + n0;
      float2 p0, p1;
      p0.x = (float)(acc[i][0] + (double)be[(size_t)e * H_ + n0 + c0 + 0]);
      p0.y = (float)(acc[i][1] + (double)be[(size_t)e * H_ + n0 + c0 + 1]);
      p1.x = (float)(acc[i][2] + (double)be[(size_t)e * H_ + n0 + c1 + 0]);
      p1.y = (float)(acc[i][3] + (double)be[(size_t)e * H_ + n0 + c1 + 1]);
      *(float2*)(dst + c0) = p0;
      *(float2*)(dst + c1) = p1;
    }
  }
}

// ---- 3. energy: bit-replica of numpy f32 logsumexp (verified R11) ----
__global__ __launch_bounds__(256) void energy_kernel(
    const float* __restrict__ out_all, const int* __restrict__ idx,
    float* __restrict__ energy) {
  const int b = blockIdx.x, j = blockIdx.y, t = threadIdx.x;
  const int e = idx[b * K_ + j];
  if (e == EXP_ID_) {
    if (t == 0) energy[b * K_ + j] = 1.0f + (float)log(2048.0);
    return;
  }
  const float* rep = out_all + ((size_t)b * E_ + EXP_ID_) * H_;
  const float* ok  = out_all + ((size_t)b * E_ + e) * H_;

  __shared__ float cs[H_];
  __shared__ float red[256];
  __shared__ float chain[128];

  float mx = -2.0f;
  for (int h = t; h < H_; h += 256) {
    float r = rep[h], o = ok[h];
    float num = r * o;
    float den = fabsf(r) * fabsf(o) + 1e-8f;
    float c = num / den;
    cs[h] = c;
    mx = fmaxf(mx, c);
  }
  red[t] = mx;
  __syncthreads();
  for (int off = 128; off > 0; off >>= 1) {
    if (t < off) red[t] = fmaxf(red[t], red[t + off]);
    __syncthreads();
  }
  const float m = red[0];
  __syncthreads();

  if (t < 128) {
    const int blk = t >> 3, jj = t & 7;
    const float* base = cs + blk * 128;
    float d0 = base[jj] - m;
    float r = (float)exp((double)d0);
#pragma unroll
    for (int q = 1; q < 16; ++q) {
      float dq = base[q * 8 + jj] - m;
      float term = (float)exp((double)dq);
      r = r + term;
    }
    chain[t] = r;
  }
  __syncthreads();

  if (t == 0) {
    float Bsum[16];
#pragma unroll
    for (int blk = 0; blk < 16; ++blk) {
      const float* c8 = chain + blk * 8;
      float s01 = c8[0] + c8[1];
      float s23 = c8[2] + c8[3];
      float s45 = c8[4] + c8[5];
      float s67 = c8[6] + c8[7];
      Bsum[blk] = (s01 + s23) + (s45 + s67);
    }
    float C[8], D[4], Ee[2];
#pragma unroll
    for (int i = 0; i < 8; ++i) C[i] = Bsum[2 * i] + Bsum[2 * i + 1];
#pragma unroll
    for (int i = 0; i < 4; ++i) D[i] = C[2 * i] + C[2 * i + 1];
#pragma unroll
    for (int i = 0; i < 2; ++i) Ee[i] = D[2 * i] + D[2 * i + 1];
    float S = Ee[0] + Ee[1];
    energy[b * K_ + j] = m + (float)log((double)S);
  }
}

// ---- 4. select: stable rank on f32 E bits (exact ties -> lower j), keep 6 ----
__global__ __launch_bounds__(256) void final_kernel(
    const float* __restrict__ out_all, const int* __restrict__ idx,
    const float* __restrict__ vals, const float* __restrict__ energy,
    float* __restrict__ out) {
  const int b = blockIdx.x;
  const int h = blockIdx.y * 256 + threadIdx.x;
  float En[K_];
#pragma unroll
  for (int j = 0; j < K_; ++j) En[j] = energy[b * K_ + j];
  double s = 0.0;
#pragma unroll
  for (int j = 0; j < K_; ++j) {
    int pos = 0;
#pragma unroll
    for (int j2 = 0; j2 < K_; ++j2)
      pos += (En[j2] < En[j]) || (En[j2] == En[j] && j2 < j);
    if (pos < KEEP_) {
      int e = idx[b * K_ + j];
      s += (double)vals[b * K_ + j] *
           (double)out_all[((size_t)b * E_ + e) * H_ + h];
    }
  }
  out[(size_t)b * H_ + h] = (float)s;
}

// ---------------- launch ----------------
extern "C" void kernel_launch(void* const* d_in, const int* in_sizes, int n_in,
                              void* d_out, int out_size, void* d_ws, size_t ws_size,
                              hipStream_t stream) {
  const float* x  = (const float*)d_in[0];
  const float* Wg = (const float*)d_in[1];
  const float* bg = (const float*)d_in[2];
  const float* We = (const float*)d_in[3];
  const float* be = (const float*)d_in[4];
  float* out = (float*)d_out;

  char* ws = (char*)d_ws;
  float* out_all = (float*)(ws + WS_OUTALL);
  int*   idx     = (int*)(ws + WS_IDX);
  float* vals    = (float*)(ws + WS_VALS);
  float* energy  = (float*)(ws + WS_ENERGY);
  int*   cnt     = (int*)(ws + WS_CNT);
  int*   rows    = (int*)(ws + WS_ROWS);

  init_cnt_kernel<<<dim3(1), dim3(64), 0, stream>>>(cnt);

  gate_kernel<<<dim3(B_), dim3(64), 0, stream>>>(x, Wg, bg, idx, vals, cnt, rows);

  gemm_expert_kernel<<<dim3(H_ / BN, B_ / BM, E_), dim3(256), 0, stream>>>(
      x, We, be, out_all, cnt, rows);

  energy_kernel<<<dim3(B_, K_), dim3(256), 0, stream>>>(out_all, idx, energy);

  final_kernel<<<dim3(B_, H_ / 256), dim3(256), 0, stream>>>(
      out_all, idx, vals, energy, out);
}

// Round 17
// 1777.626 us; speedup vs baseline: 1.0583x; 1.0233x over previous
//
#include <hip/hip_runtime.h>
#include <math.h>

#define B_ 1024
#define D_ 2048
#define H_ 2048
#define E_ 16
#define K_ 8
#define KEEP_ 6
#define EXP_ID_ 0

// ---------------- ws layout ----------------
#define WS_OUTALL 0
#define WS_IDX    134217728
#define WS_VALS   (134217728 + 32768)
#define WS_ENERGY (134217728 + 65536)
#define WS_CNT    (134217728 + 98304)
#define WS_ROWS   (134217728 + 98560)

// ---------------- 0. init: zero per-expert row counters ----------------
__global__ void init_cnt_kernel(int* __restrict__ cnt) {
  if (threadIdx.x < E_) cnt[threadIdx.x] = 0;
}

// ---------------- 1. gating: one wave per row, f64; emit row lists ----------
__global__ __launch_bounds__(64) void gate_kernel(
    const float* __restrict__ x, const float* __restrict__ Wg,
    const float* __restrict__ bg, int* __restrict__ idx, float* __restrict__ vals,
    int* __restrict__ cnt, int* __restrict__ rows) {
  const int b = blockIdx.x;
  const int lane = threadIdx.x;
  double acc[E_];
#pragma unroll
  for (int e = 0; e < E_; ++e) acc[e] = 0.0;
  for (int d = lane; d < D_; d += 64) {
    double xv = (double)x[(size_t)b * D_ + d];
    const float* w = Wg + (size_t)d * E_;
#pragma unroll
    for (int e = 0; e < E_; ++e) acc[e] = fma(xv, (double)w[e], acc[e]);
  }
  for (int off = 32; off > 0; off >>= 1) {
#pragma unroll
    for (int e = 0; e < E_; ++e) acc[e] += __shfl_down(acc[e], off, 64);
  }
  if (lane == 0) {
    double logit[E_];
#pragma unroll
    for (int e = 0; e < E_; ++e) logit[e] = acc[e] + (double)bg[e];
    double m = logit[0];
#pragma unroll
    for (int e = 1; e < E_; ++e) m = fmax(m, logit[e]);
    double p[E_], s = 0.0;
#pragma unroll
    for (int e = 0; e < E_; ++e) { p[e] = exp(logit[e] - m); s += p[e]; }
#pragma unroll
    for (int e = 0; e < E_; ++e) p[e] = p[e] / s;
    unsigned taken = 0;
    for (int j = 0; j < K_; ++j) {
      int best = -1; double bv = -1.0;
#pragma unroll
      for (int e = 0; e < E_; ++e)
        if (!((taken >> e) & 1u) && p[e] > bv) { bv = p[e]; best = e; }
      taken |= (1u << best);
      idx[b * K_ + j] = best;
      vals[b * K_ + j] = (float)bv;
    }
    taken |= 1u;   // rep expert always needed
#pragma unroll
    for (int e = 0; e < E_; ++e) {
      if ((taken >> e) & 1u) {
        int p2 = atomicAdd(&cnt[e], 1);
        rows[e * B_ + p2] = b;
      }
    }
  }
}

// ---- 2. GEMM (f64, R13 4x4 tile, single LDS buffer) + reg-carried prefetch ----
// Per-output sequential k-order identical to verified R13 -> bits identical.
#define BM 64
#define BN 64
#define BK 16

__global__ __launch_bounds__(256) void gemm_expert_kernel(
    const float* __restrict__ X, const float* __restrict__ We,
    const float* __restrict__ be, float* __restrict__ out_all,
    const int* __restrict__ cnt, const int* __restrict__ rows) {
  const int e  = blockIdx.z;
  const int nrows = cnt[e];
  const int m0 = blockIdx.y * BM;
  if (m0 >= nrows) return;
  const int n0 = blockIdx.x * BN;
  const float* Bmat = We + (size_t)e * D_ * H_;
  const int* rl = rows + e * B_;

  __shared__ double As[BM][BK + 2];   // [64][18]  9216 B
  __shared__ double Bs[BK][BN + 2];   // [16][66]  8448 B   (17664 B total)

  const int tid = threadIdx.x;
  const int tx = tid % 16, ty = tid / 16;
  const int arow  = tid >> 2;               // [0,64)
  const int acol4 = (tid & 3) * 4;          // {0,4,8,12}
  const int brow  = tid >> 4;               // [0,16)
  const int bcol4 = (tid & 15) * 4;         // {0..60}

  const int gidx = m0 + arow;
  const int grow = rl[(gidx < nrows) ? gidx : (nrows - 1)];
  const float* aptr = X + (size_t)grow * D_;
  const float* bptr = Bmat + (size_t)brow * H_ + n0 + bcol4;

  const int c0 = tx * 2;
  const int c1 = tx * 2 + 32;

  double acc[4][4] = {};

  // prologue: load tile 0 into registers
  float4 av = *(const float4*)(aptr + acol4);
  float4 bv = *(const float4*)(bptr);

  for (int k0 = 0; k0 < D_; k0 += BK) {
    __syncthreads();   // previous compute finished reading LDS
    *(double2*)&As[arow][acol4 + 0] = make_double2((double)av.x, (double)av.y);
    *(double2*)&As[arow][acol4 + 2] = make_double2((double)av.z, (double)av.w);
    *(double2*)&Bs[brow][bcol4 + 0] = make_double2((double)bv.x, (double)bv.y);
    *(double2*)&Bs[brow][bcol4 + 2] = make_double2((double)bv.z, (double)bv.w);
    __syncthreads();
    // issue tile k0+BK loads NOW: they retire under the ~1000cy of FMAs below
    if (k0 + BK < D_) {
      av = *(const float4*)(aptr + (k0 + BK) + acol4);
      bv = *(const float4*)(bptr + (size_t)(k0 + BK) * H_);
    }
#pragma unroll
    for (int kk = 0; kk < BK; kk += 2) {
      // paired A reads (b128, 16B-aligned: row stride 144B, kk even)
      double2 a0p = *(const double2*)&As[ty * 4 + 0][kk];
      double2 a1p = *(const double2*)&As[ty * 4 + 1][kk];
      double2 a2p = *(const double2*)&As[ty * 4 + 2][kk];
      double2 a3p = *(const double2*)&As[ty * 4 + 3][kk];
      double2 b01a = *(const double2*)&Bs[kk][c0];
      double2 b23a = *(const double2*)&Bs[kk][c1];
      double2 b01b = *(const double2*)&Bs[kk + 1][c0];
      double2 b23b = *(const double2*)&Bs[kk + 1][c1];
      // kk (same FMA order as R13)
      acc[0][0] = fma(a0p.x, b01a.x, acc[0][0]);
      acc[0][1] = fma(a0p.x, b01a.y, acc[0][1]);
      acc[0][2] = fma(a0p.x, b23a.x, acc[0][2]);
      acc[0][3] = fma(a0p.x, b23a.y, acc[0][3]);
      acc[1][0] = fma(a1p.x, b01a.x, acc[1][0]);
      acc[1][1] = fma(a1p.x, b01a.y, acc[1][1]);
      acc[1][2] = fma(a1p.x, b23a.x, acc[1][2]);
      acc[1][3] = fma(a1p.x, b23a.y, acc[1][3]);
      acc[2][0] = fma(a2p.x, b01a.x, acc[2][0]);
      acc[2][1] = fma(a2p.x, b01a.y, acc[2][1]);
      acc[2][2] = fma(a2p.x, b23a.x, acc[2][2]);
      acc[2][3] = fma(a2p.x, b23a.y, acc[2][3]);
      acc[3][0] = fma(a3p.x, b01a.x, acc[3][0]);
      acc[3][1] = fma(a3p.x, b01a.y, acc[3][1]);
      acc[3][2] = fma(a3p.x, b23a.x, acc[3][2]);
      acc[3][3] = fma(a3p.x, b23a.y, acc[3][3]);
      // kk+1
      acc[0][0] = fma(a0p.y, b01b.x, acc[0][0]);
      acc[0][1] = fma(a0p.y, b01b.y, acc[0][1]);
      acc[0][2] = fma(a0p.y, b23b.x, acc[0][2]);
      acc[0][3] = fma(a0p.y, b23b.y, acc[0][3]);
      acc[1][0] = fma(a1p.y, b01b.x, acc[1][0]);
      acc[1][1] = fma(a1p.y, b01b.y, acc[1][1]);
      acc[1][2] = fma(a1p.y, b23b.x, acc[1][2]);
      acc[1][3] = fma(a1p.y, b23b.y, acc[1][3]);
      acc[2][0] = fma(a2p.y, b01b.x, acc[2][0]);
      acc[2][1] = fma(a2p.y, b01b.y, acc[2][1]);
      acc[2][2] = fma(a2p.y, b23b.x, acc[2][2]);
      acc[2][3] = fma(a2p.y, b23b.y, acc[2][3]);
      acc[3][0] = fma(a3p.y, b01b.x, acc[3][0]);
      acc[3][1] = fma(a3p.y, b01b.y, acc[3][1]);
      acc[3][2] = fma(a3p.y, b23b.x, acc[3][2]);
      acc[3][3] = fma(a3p.y, b23b.y, acc[3][3]);
    }
  }
#pragma unroll
  for (int i = 0; i < 4; ++i) {
    const int ridx = m0 + ty * 4 + i;
    if (ridx < nrows) {
      const int m = rl[ridx];
      float* dst = out_all + ((size_t)m * E_ + e) * H_ + n0;
      float2 p0, p1;
      p0.x = (float)(acc[i][0] + (double)be[(size_t)e * H_ + n0 + c0 + 0]);
      p0.y = (float)(acc[i][1] + (double)be[(size_t)e * H_ + n0 + c0 + 1]);
      p1.x = (float)(acc[i][2] + (double)be[(size_t)e * H_ + n0 + c1 + 0]);
      p1.y = (float)(acc[i][3] + (double)be[(size_t)e * H_ + n0 + c1 + 1]);
      *(float2*)(dst + c0) = p0;
      *(float2*)(dst + c1) = p1;
    }
  }
}

// ---- 3. energy: bit-replica of numpy f32 logsumexp (verified R11) ----
__global__ __launch_bounds__(256) void energy_kernel(
    const float* __restrict__ out_all, const int* __restrict__ idx,
    float* __restrict__ energy) {
  const int b = blockIdx.x, j = blockIdx.y, t = threadIdx.x;
  const int e = idx[b * K_ + j];
  if (e == EXP_ID_) {
    if (t == 0) energy[b * K_ + j] = 1.0f + (float)log(2048.0);
    return;
  }
  const float* rep = out_all + ((size_t)b * E_ + EXP_ID_) * H_;
  const float* ok  = out_all + ((size_t)b * E_ + e) * H_;

  __shared__ float cs[H_];
  __shared__ float red[256];
  __shared__ float chain[128];

  float mx = -2.0f;
  for (int h = t; h < H_; h += 256) {
    float r = rep[h], o = ok[h];
    float num = r * o;
    float den = fabsf(r) * fabsf(o) + 1e-8f;
    float c = num / den;
    cs[h] = c;
    mx = fmaxf(mx, c);
  }
  red[t] = mx;
  __syncthreads();
  for (int off = 128; off > 0; off >>= 1) {
    if (t < off) red[t] = fmaxf(red[t], red[t + off]);
    __syncthreads();
  }
  const float m = red[0];
  __syncthreads();

  if (t < 128) {
    const int blk = t >> 3, jj = t & 7;
    const float* base = cs + blk * 128;
    float d0 = base[jj] - m;
    float r = (float)exp((double)d0);
#pragma unroll
    for (int q = 1; q < 16; ++q) {
      float dq = base[q * 8 + jj] - m;
      float term = (float)exp((double)dq);
      r = r + term;
    }
    chain[t] = r;
  }
  __syncthreads();

  if (t == 0) {
    float Bsum[16];
#pragma unroll
    for (int blk = 0; blk < 16; ++blk) {
      const float* c8 = chain + blk * 8;
      float s01 = c8[0] + c8[1];
      float s23 = c8[2] + c8[3];
      float s45 = c8[4] + c8[5];
      float s67 = c8[6] + c8[7];
      Bsum[blk] = (s01 + s23) + (s45 + s67);
    }
    float C[8], D[4], Ee[2];
#pragma unroll
    for (int i = 0; i < 8; ++i) C[i] = Bsum[2 * i] + Bsum[2 * i + 1];
#pragma unroll
    for (int i = 0; i < 4; ++i) D[i] = C[2 * i] + C[2 * i + 1];
#pragma unroll
    for (int i = 0; i < 2; ++i) Ee[i] = D[2 * i] + D[2 * i + 1];
    float S = Ee[0] + Ee[1];
    energy[b * K_ + j] = m + (float)log((double)S);
  }
}

// ---- 4. select: stable rank on f32 E bits (exact ties -> lower j), keep 6 ----
__global__ __launch_bounds__(256) void final_kernel(
    const float* __restrict__ out_all, const int* __restrict__ idx,
    const float* __restrict__ vals, const float* __restrict__ energy,
    float* __restrict__ out) {
  const int b = blockIdx.x;
  const int h = blockIdx.y * 256 + threadIdx.x;
  float En[K_];
#pragma unroll
  for (int j = 0; j < K_; ++j) En[j] = energy[b * K_ + j];
  double s = 0.0;
#pragma unroll
  for (int j = 0; j < K_; ++j) {
    int pos = 0;
#pragma unroll
    for (int j2 = 0; j2 < K_; ++j2)
      pos += (En[j2] < En[j]) || (En[j2] == En[j] && j2 < j);
    if (pos < KEEP_) {
      int e = idx[b * K_ + j];
      s += (double)vals[b * K_ + j] *
           (double)out_all[((size_t)b * E_ + e) * H_ + h];
    }
  }
  out[(size_t)b * H_ + h] = (float)s;
}

// ---------------- launch ----------------
extern "C" void kernel_launch(void* const* d_in, const int* in_sizes, int n_in,
                              void* d_out, int out_size, void* d_ws, size_t ws_size,
                              hipStream_t stream) {
  const float* x  = (const float*)d_in[0];
  const float* Wg = (const float*)d_in[1];
  const float* bg = (const float*)d_in[2];
  const float* We = (const float*)d_in[3];
  const float* be = (const float*)d_in[4];
  float* out = (float*)d_out;

  char* ws = (char*)d_ws;
  float* out_all = (float*)(ws + WS_OUTALL);
  int*   idx     = (int*)(ws + WS_IDX);
  float* vals    = (float*)(ws + WS_VALS);
  float* energy  = (float*)(ws + WS_ENERGY);
  int*   cnt     = (int*)(ws + WS_CNT);
  int*   rows    = (int*)(ws + WS_ROWS);

  init_cnt_kernel<<<dim3(1), dim3(64), 0, stream>>>(cnt);

  gate_kernel<<<dim3(B_), dim3(64), 0, stream>>>(x, Wg, bg, idx, vals, cnt, rows);

  gemm_expert_kernel<<<dim3(H_ / BN, B_ / BM, E_), dim3(256), 0, stream>>>(
      x, We, be, out_all, cnt, rows);

  energy_kernel<<<dim3(B_, K_), dim3(256), 0, stream>>>(out_all, idx, energy);

  final_kernel<<<dim3(B_, H_ / 256), dim3(256), 0, stream>>>(
      out_all, idx, vals, energy, out);
}

// Round 18
// 1677.198 us; speedup vs baseline: 1.1217x; 1.0599x over previous
//
#include <hip/hip_runtime.h>
#include <math.h>

#define B_ 1024
#define D_ 2048
#define H_ 2048
#define E_ 16
#define K_ 8
#define KEEP_ 6
#define EXP_ID_ 0

typedef double v4d __attribute__((ext_vector_type(4)));

// ---------------- ws layout ----------------
#define WS_OUTALL 0
#define WS_IDX    134217728
#define WS_VALS   (134217728 + 32768)
#define WS_ENERGY (134217728 + 65536)
#define WS_CNT    (134217728 + 98304)
#define WS_ROWS   (134217728 + 98560)      // E*B ints = 64 KB
#define WS_ROWTAB (134217728 + 164096)     // 256 ints
#define WS_COLTAB (134217728 + 165120)     // 256 ints
#define WS_OKFLG  (134217728 + 166144)     // 1 int

// ---------------- 0. init: counters + probe flag ----------------
__global__ void init_cnt_kernel(int* __restrict__ cnt, int* __restrict__ okflg) {
  if (threadIdx.x < E_) cnt[threadIdx.x] = 0;
  if (threadIdx.x == 0) okflg[0] = 1;
}

// ---------------- 0b. MFMA f64 layout probe (1 wave) ----------------
// Input convention staged by GEMM: lane l supplies A[l&15][l>>4], B[l>>4][l&15].
// Probe derives D's (lane,reg)->(row,col) mapping and validates the composite.
__global__ __launch_bounds__(64) void mfma_probe_kernel(
    int* __restrict__ rowtab, int* __restrict__ coltab, int* __restrict__ okflg) {
  const int l = threadIdx.x;
  const v4d z = {0.0, 0.0, 0.0, 0.0};
  // probe 1: A[i][k] = i ; B[k][j] = (k==0) -> D[i][j] = i
  double a1 = (double)(l & 15);
  double b1 = ((l >> 4) == 0) ? 1.0 : 0.0;
  v4d d1 = __builtin_amdgcn_mfma_f64_16x16x4f64(a1, b1, z, 0, 0, 0);
  // probe 2: A[i][k] = (k==0) ; B[k][j] = j -> D[i][j] = j
  double a2 = ((l >> 4) == 0) ? 1.0 : 0.0;
  double b2 = (double)(l & 15);
  v4d d2 = __builtin_amdgcn_mfma_f64_16x16x4f64(a2, b2, z, 0, 0, 0);
  // probe 3: A[i][k] = i+1 ; B[k][j] = j+1 -> D[i][j] = 4*(i+1)*(j+1)
  double a3 = (double)((l & 15) + 1);
  double b3 = (double)((l & 15) + 1);
  v4d d3 = __builtin_amdgcn_mfma_f64_16x16x4f64(a3, b3, z, 0, 0, 0);

  int ok = 1;
#pragma unroll
  for (int g = 0; g < 4; ++g) {
    int r = (int)(d1[g] + 0.5);
    int c = (int)(d2[g] + 0.5);
    if (r < 0 || r > 15 || c < 0 || c > 15) { r = 0; c = 0; ok = 0; }
    rowtab[l * 4 + g] = r;
    coltab[l * 4 + g] = c;
    double expect = 4.0 * (double)(r + 1) * (double)(c + 1);
    if (d3[g] != expect) ok = 0;
  }
  if (!ok) okflg[0] = 0;   // any lane can veto
}

// ---------------- 1. gating: one wave per row, f64; emit row lists ----------
__global__ __launch_bounds__(64) void gate_kernel(
    const float* __restrict__ x, const float* __restrict__ Wg,
    const float* __restrict__ bg, int* __restrict__ idx, float* __restrict__ vals,
    int* __restrict__ cnt, int* __restrict__ rows) {
  const int b = blockIdx.x;
  const int lane = threadIdx.x;
  double acc[E_];
#pragma unroll
  for (int e = 0; e < E_; ++e) acc[e] = 0.0;
  for (int d = lane; d < D_; d += 64) {
    double xv = (double)x[(size_t)b * D_ + d];
    const float* w = Wg + (size_t)d * E_;
#pragma unroll
    for (int e = 0; e < E_; ++e) acc[e] = fma(xv, (double)w[e], acc[e]);
  }
  for (int off = 32; off > 0; off >>= 1) {
#pragma unroll
    for (int e = 0; e < E_; ++e) acc[e] += __shfl_down(acc[e], off, 64);
  }
  if (lane == 0) {
    double logit[E_];
#pragma unroll
    for (int e = 0; e < E_; ++e) logit[e] = acc[e] + (double)bg[e];
    double m = logit[0];
#pragma unroll
    for (int e = 1; e < E_; ++e) m = fmax(m, logit[e]);
    double p[E_], s = 0.0;
#pragma unroll
    for (int e = 0; e < E_; ++e) { p[e] = exp(logit[e] - m); s += p[e]; }
#pragma unroll
    for (int e = 0; e < E_; ++e) p[e] = p[e] / s;
    unsigned taken = 0;
    for (int j = 0; j < K_; ++j) {
      int best = -1; double bv = -1.0;
#pragma unroll
      for (int e = 0; e < E_; ++e)
        if (!((taken >> e) & 1u) && p[e] > bv) { bv = p[e]; best = e; }
      taken |= (1u << best);
      idx[b * K_ + j] = best;
      vals[b * K_ + j] = (float)bv;
    }
    taken |= 1u;   // rep expert always needed
#pragma unroll
    for (int e = 0; e < E_; ++e) {
      if ((taken >> e) & 1u) {
        int p2 = atomicAdd(&cnt[e], 1);
        rows[e * B_ + p2] = b;
      }
    }
  }
}

// ---- 2. GEMM: MFMA f64 path (probe-validated) with R17 VALU fallback ----
#define BM 64
#define BN 64
#define BK 16

__global__ __launch_bounds__(256) void gemm_expert_kernel(
    const float* __restrict__ X, const float* __restrict__ We,
    const float* __restrict__ be, float* __restrict__ out_all,
    const int* __restrict__ cnt, const int* __restrict__ rows,
    const int* __restrict__ rowtab, const int* __restrict__ coltab,
    const int* __restrict__ okflg) {
  const int e  = blockIdx.z;
  const int nrows = cnt[e];
  const int m0 = blockIdx.y * BM;
  if (m0 >= nrows) return;
  const int n0 = blockIdx.x * BN;
  const float* Bmat = We + (size_t)e * D_ * H_;
  const int* rl = rows + e * B_;

  __shared__ double As[BM][BK + 2];   // [64][18]  9216 B
  __shared__ double Bs[BK][BN + 2];   // [16][66]  8448 B

  const int tid = threadIdx.x;
  const int arow  = tid >> 2;               // [0,64)
  const int acol4 = (tid & 3) * 4;          // {0,4,8,12}
  const int brow  = tid >> 4;               // [0,16)
  const int bcol4 = (tid & 15) * 4;         // {0..60}

  const int gidx = m0 + arow;
  const int grow = rl[(gidx < nrows) ? gidx : (nrows - 1)];
  const float* aptr = X + (size_t)grow * D_;
  const float* bptr = Bmat + (size_t)brow * H_ + n0 + bcol4;

  const bool use_mfma = (okflg[0] == 1);

  if (use_mfma) {
    const int lane = tid & 63;
    const int wave = tid >> 6;       // rows wave*16 .. +15
    const int lr = lane & 15;
    const int lq = lane >> 4;

    v4d acc[4];
#pragma unroll
    for (int c = 0; c < 4; ++c) acc[c] = (v4d){0.0, 0.0, 0.0, 0.0};

    float4 av = *(const float4*)(aptr + acol4);
    float4 bv = *(const float4*)(bptr);

    for (int k0 = 0; k0 < D_; k0 += BK) {
      __syncthreads();
      *(double2*)&As[arow][acol4 + 0] = make_double2((double)av.x, (double)av.y);
      *(double2*)&As[arow][acol4 + 2] = make_double2((double)av.z, (double)av.w);
      *(double2*)&Bs[brow][bcol4 + 0] = make_double2((double)bv.x, (double)bv.y);
      *(double2*)&Bs[brow][bcol4 + 2] = make_double2((double)bv.z, (double)bv.w);
      __syncthreads();
      if (k0 + BK < D_) {
        av = *(const float4*)(aptr + (k0 + BK) + acol4);
        bv = *(const float4*)(bptr + (size_t)(k0 + BK) * H_);
      }
#pragma unroll
      for (int k4 = 0; k4 < BK; k4 += 4) {
        double a = As[wave * 16 + lr][k4 + lq];
#pragma unroll
        for (int c = 0; c < 4; ++c) {
          double bb = Bs[k4 + lq][c * 16 + lr];
          acc[c] = __builtin_amdgcn_mfma_f64_16x16x4f64(a, bb, acc[c], 0, 0, 0);
        }
      }
    }
    // epilogue via probed D layout
    int drow[4], dcol[4];
#pragma unroll
    for (int g = 0; g < 4; ++g) {
      drow[g] = rowtab[lane * 4 + g];
      dcol[g] = coltab[lane * 4 + g];
    }
#pragma unroll
    for (int c = 0; c < 4; ++c) {
#pragma unroll
      for (int g = 0; g < 4; ++g) {
        const int ridx = m0 + wave * 16 + drow[g];
        if (ridx < nrows) {
          const int mrow = rl[ridx];
          const int col = n0 + c * 16 + dcol[g];
          out_all[((size_t)mrow * E_ + e) * H_ + col] =
              (float)(acc[c][g] + (double)be[(size_t)e * H_ + col]);
        }
      }
    }
    return;
  }

  // ---------- VALU fallback: R17 verbatim (bit-identical to R13) ----------
  const int tx = tid % 16, ty = tid / 16;
  const int c0 = tx * 2;
  const int c1 = tx * 2 + 32;

  double acc[4][4] = {};

  float4 av = *(const float4*)(aptr + acol4);
  float4 bv = *(const float4*)(bptr);

  for (int k0 = 0; k0 < D_; k0 += BK) {
    __syncthreads();
    *(double2*)&As[arow][acol4 + 0] = make_double2((double)av.x, (double)av.y);
    *(double2*)&As[arow][acol4 + 2] = make_double2((double)av.z, (double)av.w);
    *(double2*)&Bs[brow][bcol4 + 0] = make_double2((double)bv.x, (double)bv.y);
    *(double2*)&Bs[brow][bcol4 + 2] = make_double2((double)bv.z, (double)bv.w);
    __syncthreads();
    if (k0 + BK < D_) {
      av = *(const float4*)(aptr + (k0 + BK) + acol4);
      bv = *(const float4*)(bptr + (size_t)(k0 + BK) * H_);
    }
#pragma unroll
    for (int kk = 0; kk < BK; kk += 2) {
      double2 a0p = *(const double2*)&As[ty * 4 + 0][kk];
      double2 a1p = *(const double2*)&As[ty * 4 + 1][kk];
      double2 a2p = *(const double2*)&As[ty * 4 + 2][kk];
      double2 a3p = *(const double2*)&As[ty * 4 + 3][kk];
      double2 b01a = *(const double2*)&Bs[kk][c0];
      double2 b23a = *(const double2*)&Bs[kk][c1];
      double2 b01b = *(const double2*)&Bs[kk + 1][c0];
      double2 b23b = *(const double2*)&Bs[kk + 1][c1];
      acc[0][0] = fma(a0p.x, b01a.x, acc[0][0]);
      acc[0][1] = fma(a0p.x, b01a.y, acc[0][1]);
      acc[0][2] = fma(a0p.x, b23a.x, acc[0][2]);
      acc[0][3] = fma(a0p.x, b23a.y, acc[0][3]);
      acc[1][0] = fma(a1p.x, b01a.x, acc[1][0]);
      acc[1][1] = fma(a1p.x, b01a.y, acc[1][1]);
      acc[1][2] = fma(a1p.x, b23a.x, acc[1][2]);
      acc[1][3] = fma(a1p.x, b23a.y, acc[1][3]);
      acc[2][0] = fma(a2p.x, b01a.x, acc[2][0]);
      acc[2][1] = fma(a2p.x, b01a.y, acc[2][1]);
      acc[2][2] = fma(a2p.x, b23a.x, acc[2][2]);
      acc[2][3] = fma(a2p.x, b23a.y, acc[2][3]);
      acc[3][0] = fma(a3p.x, b01a.x, acc[3][0]);
      acc[3][1] = fma(a3p.x, b01a.y, acc[3][1]);
      acc[3][2] = fma(a3p.x, b23a.x, acc[3][2]);
      acc[3][3] = fma(a3p.x, b23a.y, acc[3][3]);
      acc[0][0] = fma(a0p.y, b01b.x, acc[0][0]);
      acc[0][1] = fma(a0p.y, b01b.y, acc[0][1]);
      acc[0][2] = fma(a0p.y, b23b.x, acc[0][2]);
      acc[0][3] = fma(a0p.y, b23b.y, acc[0][3]);
      acc[1][0] = fma(a1p.y, b01b.x, acc[1][0]);
      acc[1][1] = fma(a1p.y, b01b.y, acc[1][1]);
      acc[1][2] = fma(a1p.y, b23b.x, acc[1][2]);
      acc[1][3] = fma(a1p.y, b23b.y, acc[1][3]);
      acc[2][0] = fma(a2p.y, b01b.x, acc[2][0]);
      acc[2][1] = fma(a2p.y, b01b.y, acc[2][1]);
      acc[2][2] = fma(a2p.y, b23b.x, acc[2][2]);
      acc[2][3] = fma(a2p.y, b23b.y, acc[2][3]);
      acc[3][0] = fma(a3p.y, b01b.x, acc[3][0]);
      acc[3][1] = fma(a3p.y, b01b.y, acc[3][1]);
      acc[3][2] = fma(a3p.y, b23b.x, acc[3][2]);
      acc[3][3] = fma(a3p.y, b23b.y, acc[3][3]);
    }
  }
#pragma unroll
  for (int i = 0; i < 4; ++i) {
    const int ridx = m0 + ty * 4 + i;
    if (ridx < nrows) {
      const int m = rl[ridx];
      float* dst = out_all + ((size_t)m * E_ + e) * H_ + n0;
      float2 p0, p1;
      p0.x = (float)(acc[i][0] + (double)be[(size_t)e * H_ + n0 + c0 + 0]);
      p0.y = (float)(acc[i][1] + (double)be[(size_t)e * H_ + n0 + c0 + 1]);
      p1.x = (float)(acc[i][2] + (double)be[(size_t)e * H_ + n0 + c1 + 0]);
      p1.y = (float)(acc[i][3] + (double)be[(size_t)e * H_ + n0 + c1 + 1]);
      *(float2*)(dst + c0) = p0;
      *(float2*)(dst + c1) = p1;
    }
  }
}

// ---- 3. energy: bit-replica of numpy f32 logsumexp (verified R11) ----
__global__ __launch_bounds__(256) void energy_kernel(
    const float* __restrict__ out_all, const int* __restrict__ idx,
    float* __restrict__ energy) {
  const int b = blockIdx.x, j = blockIdx.y, t = threadIdx.x;
  const int e = idx[b * K_ + j];
  if (e == EXP_ID_) {
    if (t == 0) energy[b * K_ + j] = 1.0f + (float)log(2048.0);
    return;
  }
  const float* rep = out_all + ((size_t)b * E_ + EXP_ID_) * H_;
  const float* ok  = out_all + ((size_t)b * E_ + e) * H_;

  __shared__ float cs[H_];
  __shared__ float red[256];
  __shared__ float chain[128];

  float mx = -2.0f;
  for (int h = t; h < H_; h += 256) {
    float r = rep[h], o = ok[h];
    float num = r * o;
    float den = fabsf(r) * fabsf(o) + 1e-8f;
    float c = num / den;
    cs[h] = c;
    mx = fmaxf(mx, c);
  }
  red[t] = mx;
  __syncthreads();
  for (int off = 128; off > 0; off >>= 1) {
    if (t < off) red[t] = fmaxf(red[t], red[t + off]);
    __syncthreads();
  }
  const float m = red[0];
  __syncthreads();

  if (t < 128) {
    const int blk = t >> 3, jj = t & 7;
    const float* base = cs + blk * 128;
    float d0 = base[jj] - m;
    float r = (float)exp((double)d0);
#pragma unroll
    for (int q = 1; q < 16; ++q) {
      float dq = base[q * 8 + jj] - m;
      float term = (float)exp((double)dq);
      r = r + term;
    }
    chain[t] = r;
  }
  __syncthreads();

  if (t == 0) {
    float Bsum[16];
#pragma unroll
    for (int blk = 0; blk < 16; ++blk) {
      const float* c8 = chain + blk * 8;
      float s01 = c8[0] + c8[1];
      float s23 = c8[2] + c8[3];
      float s45 = c8[4] + c8[5];
      float s67 = c8[6] + c8[7];
      Bsum[blk] = (s01 + s23) + (s45 + s67);
    }
    float C[8], D[4], Ee[2];
#pragma unroll
    for (int i = 0; i < 8; ++i) C[i] = Bsum[2 * i] + Bsum[2 * i + 1];
#pragma unroll
    for (int i = 0; i < 4; ++i) D[i] = C[2 * i] + C[2 * i + 1];
#pragma unroll
    for (int i = 0; i < 2; ++i) Ee[i] = D[2 * i] + D[2 * i + 1];
    float S = Ee[0] + Ee[1];
    energy[b * K_ + j] = m + (float)log((double)S);
  }
}

// ---- 4. select: stable rank on f32 E bits (exact ties -> lower j), keep 6 ----
__global__ __launch_bounds__(256) void final_kernel(
    const float* __restrict__ out_all, const int* __restrict__ idx,
    const float* __restrict__ vals, const float* __restrict__ energy,
    float* __restrict__ out) {
  const int b = blockIdx.x;
  const int h = blockIdx.y * 256 + threadIdx.x;
  float En[K_];
#pragma unroll
  for (int j = 0; j < K_; ++j) En[j] = energy[b * K_ + j];
  double s = 0.0;
#pragma unroll
  for (int j = 0; j < K_; ++j) {
    int pos = 0;
#pragma unroll
    for (int j2 = 0; j2 < K_; ++j2)
      pos += (En[j2] < En[j]) || (En[j2] == En[j] && j2 < j);
    if (pos < KEEP_) {
      int e = idx[b * K_ + j];
      s += (double)vals[b * K_ + j] *
           (double)out_all[((size_t)b * E_ + e) * H_ + h];
    }
  }
  out[(size_t)b * H_ + h] = (float)s;
}

// ---------------- launch ----------------
extern "C" void kernel_launch(void* const* d_in, const int* in_sizes, int n_in,
                              void* d_out, int out_size, void* d_ws, size_t ws_size,
                              hipStream_t stream) {
  const float* x  = (const float*)d_in[0];
  const float* Wg = (const float*)d_in[1];
  const float* bg = (const float*)d_in[2];
  const float* We = (const float*)d_in[3];
  const float* be = (const float*)d_in[4];
  float* out = (float*)d_out;

  char* ws = (char*)d_ws;
  float* out_all = (float*)(ws + WS_OUTALL);
  int*   idx     = (int*)(ws + WS_IDX);
  float* vals    = (float*)(ws + WS_VALS);
  float* energy  = (float*)(ws + WS_ENERGY);
  int*   cnt     = (int*)(ws + WS_CNT);
  int*   rows    = (int*)(ws + WS_ROWS);
  int*   rowtab  = (int*)(ws + WS_ROWTAB);
  int*   coltab  = (int*)(ws + WS_COLTAB);
  int*   okflg   = (int*)(ws + WS_OKFLG);

  init_cnt_kernel<<<dim3(1), dim3(64), 0, stream>>>(cnt, okflg);

  mfma_probe_kernel<<<dim3(1), dim3(64), 0, stream>>>(rowtab, coltab, okflg);

  gate_kernel<<<dim3(B_), dim3(64), 0, stream>>>(x, Wg, bg, idx, vals, cnt, rows);

  gemm_expert_kernel<<<dim3(H_ / BN, B_ / BM, E_), dim3(256), 0, stream>>>(
      x, We, be, out_all, cnt, rows, rowtab, coltab, okflg);

  energy_kernel<<<dim3(B_, K_), dim3(256), 0, stream>>>(out_all, idx, energy);

  final_kernel<<<dim3(B_, H_ / 256), dim3(256), 0, stream>>>(
      out_all, idx, vals, energy, out);
}

// Round 19
// 1483.463 us; speedup vs baseline: 1.2682x; 1.1306x over previous
//
#include <hip/hip_runtime.h>
#include <math.h>

#define B_ 1024
#define D_ 2048
#define H_ 2048
#define E_ 16
#define K_ 8
#define KEEP_ 6
#define EXP_ID_ 0

typedef double v4d __attribute__((ext_vector_type(4)));

// ---------------- ws layout ----------------
#define WS_OUTALL 0
#define WS_IDX    134217728
#define WS_VALS   (134217728 + 32768)
#define WS_ENERGY (134217728 + 65536)
#define WS_CNT    (134217728 + 98304)
#define WS_ROWS   (134217728 + 98560)      // E*B ints = 64 KB
#define WS_ROWTAB (134217728 + 164096)     // 256 ints
#define WS_COLTAB (134217728 + 165120)     // 256 ints
#define WS_OKFLG  (134217728 + 166144)     // 1 int (diagnostic)

// ---------------- 0. init: counters + probe flag ----------------
__global__ void init_cnt_kernel(int* __restrict__ cnt, int* __restrict__ okflg) {
  if (threadIdx.x < E_) cnt[threadIdx.x] = 0;
  if (threadIdx.x == 0) okflg[0] = 1;
}

// ---------------- 0b. MFMA f64 layout probe (1 wave) ----------------
// Input convention staged by GEMM: lane l supplies A[l&15][l>>4], B[l>>4][l&15].
// Probe derives D's (lane,reg)->(row,col) mapping; validated composite R18.
__global__ __launch_bounds__(64) void mfma_probe_kernel(
    int* __restrict__ rowtab, int* __restrict__ coltab, int* __restrict__ okflg) {
  const int l = threadIdx.x;
  const v4d z = {0.0, 0.0, 0.0, 0.0};
  double a1 = (double)(l & 15);
  double b1 = ((l >> 4) == 0) ? 1.0 : 0.0;
  v4d d1 = __builtin_amdgcn_mfma_f64_16x16x4f64(a1, b1, z, 0, 0, 0);
  double a2 = ((l >> 4) == 0) ? 1.0 : 0.0;
  double b2 = (double)(l & 15);
  v4d d2 = __builtin_amdgcn_mfma_f64_16x16x4f64(a2, b2, z, 0, 0, 0);
  double a3 = (double)((l & 15) + 1);
  double b3 = (double)((l & 15) + 1);
  v4d d3 = __builtin_amdgcn_mfma_f64_16x16x4f64(a3, b3, z, 0, 0, 0);

  int ok = 1;
#pragma unroll
  for (int g = 0; g < 4; ++g) {
    int r = (int)(d1[g] + 0.5);
    int c = (int)(d2[g] + 0.5);
    if (r < 0 || r > 15 || c < 0 || c > 15) { r = 0; c = 0; ok = 0; }
    rowtab[l * 4 + g] = r;
    coltab[l * 4 + g] = c;
    double expect = 4.0 * (double)(r + 1) * (double)(c + 1);
    if (d3[g] != expect) ok = 0;
  }
  if (!ok) okflg[0] = 0;
}

// ---------------- 1. gating: one wave per row, f64; emit row lists ----------
__global__ __launch_bounds__(64) void gate_kernel(
    const float* __restrict__ x, const float* __restrict__ Wg,
    const float* __restrict__ bg, int* __restrict__ idx, float* __restrict__ vals,
    int* __restrict__ cnt, int* __restrict__ rows) {
  const int b = blockIdx.x;
  const int lane = threadIdx.x;
  double acc[E_];
#pragma unroll
  for (int e = 0; e < E_; ++e) acc[e] = 0.0;
  for (int d = lane; d < D_; d += 64) {
    double xv = (double)x[(size_t)b * D_ + d];
    const float* w = Wg + (size_t)d * E_;
#pragma unroll
    for (int e = 0; e < E_; ++e) acc[e] = fma(xv, (double)w[e], acc[e]);
  }
  for (int off = 32; off > 0; off >>= 1) {
#pragma unroll
    for (int e = 0; e < E_; ++e) acc[e] += __shfl_down(acc[e], off, 64);
  }
  if (lane == 0) {
    double logit[E_];
#pragma unroll
    for (int e = 0; e < E_; ++e) logit[e] = acc[e] + (double)bg[e];
    double m = logit[0];
#pragma unroll
    for (int e = 1; e < E_; ++e) m = fmax(m, logit[e]);
    double p[E_], s = 0.0;
#pragma unroll
    for (int e = 0; e < E_; ++e) { p[e] = exp(logit[e] - m); s += p[e]; }
#pragma unroll
    for (int e = 0; e < E_; ++e) p[e] = p[e] / s;
    unsigned taken = 0;
    for (int j = 0; j < K_; ++j) {
      int best = -1; double bv = -1.0;
#pragma unroll
      for (int e = 0; e < E_; ++e)
        if (!((taken >> e) & 1u) && p[e] > bv) { bv = p[e]; best = e; }
      taken |= (1u << best);
      idx[b * K_ + j] = best;
      vals[b * K_ + j] = (float)bv;
    }
    taken |= 1u;   // rep expert always needed
#pragma unroll
    for (int e = 0; e < E_; ++e) {
      if ((taken >> e) & 1u) {
        int p2 = atomicAdd(&cnt[e], 1);
        rows[e * B_ + p2] = b;
      }
    }
  }
}

// ---- 2. GEMM: f64 MFMA only (probe-table epilogue), row-gathered ----
// MFMA issue order per output identical to R18 -> out_all bits identical.
#define BM 64
#define BN 64
#define BK 16

__global__ __launch_bounds__(256) void gemm_expert_kernel(
    const float* __restrict__ X, const float* __restrict__ We,
    const float* __restrict__ be, float* __restrict__ out_all,
    const int* __restrict__ cnt, const int* __restrict__ rows,
    const int* __restrict__ rowtab, const int* __restrict__ coltab) {
  const int e  = blockIdx.z;
  const int nrows = cnt[e];
  const int m0 = blockIdx.y * BM;
  if (m0 >= nrows) return;
  const int n0 = blockIdx.x * BN;
  const float* Bmat = We + (size_t)e * D_ * H_;
  const int* rl = rows + e * B_;

  __shared__ double As[BM][BK + 2];   // [64][18]  9216 B
  __shared__ double Bs[BK][BN + 2];   // [16][66]  8448 B

  const int tid = threadIdx.x;
  const int arow  = tid >> 2;               // [0,64)
  const int acol4 = (tid & 3) * 4;          // {0,4,8,12}
  const int brow  = tid >> 4;               // [0,16)
  const int bcol4 = (tid & 15) * 4;         // {0..60}

  const int gidx = m0 + arow;
  const int grow = rl[(gidx < nrows) ? gidx : (nrows - 1)];
  const float* aptr = X + (size_t)grow * D_;
  const float* bptr = Bmat + (size_t)brow * H_ + n0 + bcol4;

  const int lane = tid & 63;
  const int wave = tid >> 6;       // rows wave*16 .. +15
  const int lr = lane & 15;
  const int lq = lane >> 4;

  v4d acc[4];
#pragma unroll
  for (int c = 0; c < 4; ++c) acc[c] = (v4d){0.0, 0.0, 0.0, 0.0};

  float4 av = *(const float4*)(aptr + acol4);
  float4 bv = *(const float4*)(bptr);

  for (int k0 = 0; k0 < D_; k0 += BK) {
    __syncthreads();
    *(double2*)&As[arow][acol4 + 0] = make_double2((double)av.x, (double)av.y);
    *(double2*)&As[arow][acol4 + 2] = make_double2((double)av.z, (double)av.w);
    *(double2*)&Bs[brow][bcol4 + 0] = make_double2((double)bv.x, (double)bv.y);
    *(double2*)&Bs[brow][bcol4 + 2] = make_double2((double)bv.z, (double)bv.w);
    __syncthreads();
    if (k0 + BK < D_) {
      av = *(const float4*)(aptr + (k0 + BK) + acol4);
      bv = *(const float4*)(bptr + (size_t)(k0 + BK) * H_);
    }
#pragma unroll
    for (int k4 = 0; k4 < BK; k4 += 4) {
      double a = As[wave * 16 + lr][k4 + lq];
#pragma unroll
      for (int c = 0; c < 4; ++c) {
        double bb = Bs[k4 + lq][c * 16 + lr];
        acc[c] = __builtin_amdgcn_mfma_f64_16x16x4f64(a, bb, acc[c], 0, 0, 0);
      }
    }
  }
  // epilogue via probed D layout
  int drow[4], dcol[4];
#pragma unroll
  for (int g = 0; g < 4; ++g) {
    drow[g] = rowtab[lane * 4 + g];
    dcol[g] = coltab[lane * 4 + g];
  }
#pragma unroll
  for (int c = 0; c < 4; ++c) {
#pragma unroll
    for (int g = 0; g < 4; ++g) {
      const int ridx = m0 + wave * 16 + drow[g];
      if (ridx < nrows) {
        const int mrow = rl[ridx];
        const int col = n0 + c * 16 + dcol[g];
        out_all[((size_t)mrow * E_ + e) * H_ + col] =
            (float)(acc[c][g] + (double)be[(size_t)e * H_ + col]);
      }
    }
  }
}

// ---- 3. energy: bit-replica of numpy f32 logsumexp (verified R11) ----
__global__ __launch_bounds__(256) void energy_kernel(
    const float* __restrict__ out_all, const int* __restrict__ idx,
    float* __restrict__ energy) {
  const int b = blockIdx.x, j = blockIdx.y, t = threadIdx.x;
  const int e = idx[b * K_ + j];
  if (e == EXP_ID_) {
    if (t == 0) energy[b * K_ + j] = 1.0f + (float)log(2048.0);
    return;
  }
  const float* rep = out_all + ((size_t)b * E_ + EXP_ID_) * H_;
  const float* ok  = out_all + ((size_t)b * E_ + e) * H_;

  __shared__ float cs[H_];
  __shared__ float red[256];
  __shared__ float chain[128];

  float mx = -2.0f;
  for (int h = t; h < H_; h += 256) {
    float r = rep[h], o = ok[h];
    float num = r * o;
    float den = fabsf(r) * fabsf(o) + 1e-8f;
    float c = num / den;
    cs[h] = c;
    mx = fmaxf(mx, c);
  }
  red[t] = mx;
  __syncthreads();
  for (int off = 128; off > 0; off >>= 1) {
    if (t < off) red[t] = fmaxf(red[t], red[t + off]);
    __syncthreads();
  }
  const float m = red[0];
  __syncthreads();

  if (t < 128) {
    const int blk = t >> 3, jj = t & 7;
    const float* base = cs + blk * 128;
    float d0 = base[jj] - m;
    float r = (float)exp((double)d0);
#pragma unroll
    for (int q = 1; q < 16; ++q) {
      float dq = base[q * 8 + jj] - m;
      float term = (float)exp((double)dq);
      r = r + term;
    }
    chain[t] = r;
  }
  __syncthreads();

  if (t == 0) {
    float Bsum[16];
#pragma unroll
    for (int blk = 0; blk < 16; ++blk) {
      const float* c8 = chain + blk * 8;
      float s01 = c8[0] + c8[1];
      float s23 = c8[2] + c8[3];
      float s45 = c8[4] + c8[5];
      float s67 = c8[6] + c8[7];
      Bsum[blk] = (s01 + s23) + (s45 + s67);
    }
    float C[8], D[4], Ee[2];
#pragma unroll
    for (int i = 0; i < 8; ++i) C[i] = Bsum[2 * i] + Bsum[2 * i + 1];
#pragma unroll
    for (int i = 0; i < 4; ++i) D[i] = C[2 * i] + C[2 * i + 1];
#pragma unroll
    for (int i = 0; i < 2; ++i) Ee[i] = D[2 * i] + D[2 * i + 1];
    float S = Ee[0] + Ee[1];
    energy[b * K_ + j] = m + (float)log((double)S);
  }
}

// ---- 4. select: stable rank on f32 E bits (exact ties -> lower j), keep 6 ----
__global__ __launch_bounds__(256) void final_kernel(
    const float* __restrict__ out_all, const int* __restrict__ idx,
    const float* __restrict__ vals, const float* __restrict__ energy,
    float* __restrict__ out) {
  const int b = blockIdx.x;
  const int h = blockIdx.y * 256 + threadIdx.x;
  float En[K_];
#pragma unroll
  for (int j = 0; j < K_; ++j) En[j] = energy[b * K_ + j];
  double s = 0.0;
#pragma unroll
  for (int j = 0; j < K_; ++j) {
    int pos = 0;
#pragma unroll
    for (int j2 = 0; j2 < K_; ++j2)
      pos += (En[j2] < En[j]) || (En[j2] == En[j] && j2 < j);
    if (pos < KEEP_) {
      int e = idx[b * K_ + j];
      s += (double)vals[b * K_ + j] *
           (double)out_all[((size_t)b * E_ + e) * H_ + h];
    }
  }
  out[(size_t)b * H_ + h] = (float)s;
}

// ---------------- launch ----------------
extern "C" void kernel_launch(void* const* d_in, const int* in_sizes, int n_in,
                              void* d_out, int out_size, void* d_ws, size_t ws_size,
                              hipStream_t stream) {
  const float* x  = (const float*)d_in[0];
  const float* Wg = (const float*)d_in[1];
  const float* bg = (const float*)d_in[2];
  const float* We = (const float*)d_in[3];
  const float* be = (const float*)d_in[4];
  float* out = (float*)d_out;

  char* ws = (char*)d_ws;
  float* out_all = (float*)(ws + WS_OUTALL);
  int*   idx     = (int*)(ws + WS_IDX);
  float* vals    = (float*)(ws + WS_VALS);
  float* energy  = (float*)(ws + WS_ENERGY);
  int*   cnt     = (int*)(ws + WS_CNT);
  int*   rows    = (int*)(ws + WS_ROWS);
  int*   rowtab  = (int*)(ws + WS_ROWTAB);
  int*   coltab  = (int*)(ws + WS_COLTAB);
  int*   okflg   = (int*)(ws + WS_OKFLG);

  init_cnt_kernel<<<dim3(1), dim3(64), 0, stream>>>(cnt, okflg);

  mfma_probe_kernel<<<dim3(1), dim3(64), 0, stream>>>(rowtab, coltab, okflg);

  gate_kernel<<<dim3(B_), dim3(64), 0, stream>>>(x, Wg, bg, idx, vals, cnt, rows);

  gemm_expert_kernel<<<dim3(H_ / BN, B_ / BM, E_), dim3(256), 0, stream>>>(
      x, We, be, out_all, cnt, rows, rowtab, coltab);

  energy_kernel<<<dim3(B_, K_), dim3(256), 0, stream>>>(out_all, idx, energy);

  final_kernel<<<dim3(B_, H_ / 256), dim3(256), 0, stream>>>(
      out_all, idx, vals, energy, out);
}